// Round 1
// baseline (618.852 us; speedup 1.0000x reference)
//
#include <hip/hip_runtime.h>
#include <math.h>

// Problem constants: B=2, S=2048, D=512, H=8
#define BB 2
#define SS 2048
#define D_ 512
#define H_ 8
#define MS (BB * SS)   // 4096 rows (b,s)
#define HD (H_ * D_)   // 4096 concat dim

typedef short bf16x8 __attribute__((ext_vector_type(8)));
typedef float f32x4 __attribute__((ext_vector_type(4)));

// ---- bf16 helpers (RNE) ----
__device__ inline unsigned short f2bf(float f) {
    union { float f; unsigned u; } x{f};
    unsigned r = x.u + 0x7fff + ((x.u >> 16) & 1);
    return (unsigned short)(r >> 16);
}
__device__ inline float bf2f(unsigned short u) {
    union { unsigned u; float f; } x{(unsigned)u << 16};
    return x.f;
}

// ---- static workspace ----
constexpr size_t SZ_X   = (size_t)MS * D_ * 2;           // 4 MiB per X (bf16)
constexpr size_t SZ_W   = (size_t)H_ * D_ * D_ * 2;      // 4 MiB per W^T
constexpr size_t SZ_WZ  = (size_t)HD * D_ * 2;           // 4 MiB Wz^T
constexpr size_t SZ_QK  = (size_t)H_ * MS * D_ * 2;      // 32 MiB q or k
constexpr size_t SZ_SC  = (size_t)H_ * BB * SS * SS * 2; // 128 MiB E = exp(scores) bf16
constexpr size_t SZ_Z   = (size_t)MS * HD * 2;           // 32 MiB z concat
constexpr size_t SZ_OP  = (size_t)2 * MS * D_ * 4;       // 16 MiB out-proj K-split partials
constexpr size_t SZ_LV  = (size_t)H_ * BB * SS * 4;      // 128 KiB 1/rowsum
constexpr size_t OFF_XQ  = 0;
constexpr size_t OFF_XK  = OFF_XQ + SZ_X;
constexpr size_t OFF_XV  = OFF_XK + SZ_X;
constexpr size_t OFF_WQT = OFF_XV + SZ_X;
constexpr size_t OFF_WKT = OFF_WQT + SZ_W;
constexpr size_t OFF_WVT = OFF_WKT + SZ_W;
constexpr size_t OFF_WZT = OFF_WVT + SZ_W;
constexpr size_t OFF_QB  = OFF_WZT + SZ_WZ;
constexpr size_t OFF_KB  = OFF_QB + SZ_QK;
constexpr size_t OFF_VT  = OFF_KB + SZ_QK;
constexpr size_t OFF_SC  = OFF_VT + SZ_QK;
constexpr size_t OFF_Z   = OFF_SC + SZ_SC;
constexpr size_t OFF_OP  = OFF_Z + SZ_Z;
constexpr size_t OFF_LV  = OFF_OP + SZ_OP;
constexpr size_t WS_TOTAL = OFF_LV + SZ_LV;
__device__ __align__(256) unsigned char g_ws[WS_TOTAL];

// ---- async global->LDS, 16 B/lane; LDS dest = wave-uniform base + lane*16 ----
__device__ inline void gl2lds16(const unsigned short* g, unsigned short* l) {
    __builtin_amdgcn_global_load_lds(
        (const __attribute__((address_space(1))) void*)g,
        (__attribute__((address_space(3))) void*)l, 16, 0, 0);
}

// ================  256x128 pipelined bf16 NT GEMM (T3+T4+T5)  ================
// C = f(alpha * A @ B'^T), A [M,K] K-contig, B' [N,K] K-contig, out bf16.
// BM=256 BN=128 BK=64. 8 waves 4Mx2N, each 64x64 via 4x4 mfma_f32_16x16x32_bf16.
// 3 LDS tile slots (144 KiB), prefetch distance 2 K-tiles: during tile t we
// stage tile t+2; at each tile boundary s_waitcnt vmcnt(6) retires tile t+1's
// 6 per-wave loads while t+2's 6 stay in flight (never vmcnt(0) mid-loop).
// 2 phases/tile: {stage 3 gl2lds; ds_read frags; s_barrier; setprio(1);
// 16 MFMA; setprio(0); s_barrier}. Raw barriers (no implicit vmcnt drain).
// Slot-overwrite safety: slot[(t+2)%3] last read in tile t-1, two barriers
// earlier; each wave's ds_reads drain (MFMA data-dep) before post-MFMA barrier.
// LDS rows of 64 shorts, quad slot j^(row&7) -> b128 reads conflict-free (r5).
__global__ __launch_bounds__(512) void gemm256_k(
    const unsigned short* __restrict__ A, const unsigned short* __restrict__ B,
    unsigned short* __restrict__ C, int K, int ldA, int ldB, int ldC,
    long sA1, long sA2, long sB1, long sB2, long sC1, long sC2, int d2,
    float alpha, int doExp, const float* __restrict__ rowScale, long sR1, long sR2)
{
    __shared__ unsigned short As[3][256 * 64];   // 3 x 32 KiB
    __shared__ unsigned short Bs[3][128 * 64];   // 3 x 16 KiB
    // XCD-aware swizzle (same scheme as 128^2 kernel; all grids %8==0)
    const int gx = gridDim.x, gy = gridDim.y, gz = gridDim.z;
    int bx, by, bz;
    if (((gy * gz) & 7) == 0) {
        const long L = blockIdx.x + (long)gx * (blockIdx.y + (long)gy * blockIdx.z);
        const int d = (int)(L & 7);
        const long s = L >> 3;
        bx = (int)(s % gx);
        const long yz = d + 8 * (s / gx);
        by = (int)(yz % gy);
        bz = (int)(yz / gy);
    } else {
        bx = blockIdx.x; by = blockIdx.y; bz = blockIdx.z;
    }
    const int z1 = bz / d2, z2 = bz % d2;
    A += z1 * sA1 + z2 * sA2;
    B += z1 * sB1 + z2 * sB2;
    const long cOff = z1 * sC1 + z2 * sC2;
    const long rsOff = z1 * sR1 + z2 * sR2;
    const int m0 = by * 256, n0 = bx * 128;
    const int tid = threadIdx.x;
    const int w = tid >> 6, l = tid & 63;

    // staging: wave w owns A rows [w*32,w*32+32) (4 instrs), B rows [w*16,+16) (2)
    const int sr = l >> 3;
    const int sq = (l & 7) ^ sr;                 // pre-swizzled global quad
    const unsigned short* gA = A + (long)(m0 + w * 32 + sr) * ldA + sq * 8;
    const unsigned short* gB = B + (long)(n0 + w * 16 + sr) * ldB + sq * 8;

    // fragment bases: lane reads row base + quad slot ((s*4+q)^(l&7))*8
    const int wm = w >> 1, wn = w & 1;
    const int q = l >> 4, sl = l & 7;
    const int mA = wm * 64 + (l & 15);
    const int nB = wn * 64 + (l & 15);
    const int o0 = ((q)     ^ sl) * 8;
    const int o1 = ((q + 4) ^ sl) * 8;

    const int nK = K >> 6;
    f32x4 acc[4][4] = {};

    auto STAGE = [&](int t, int h) {   // h=0: A rows 0..15 + B rows 0..7 ; h=1: rest
        const int s = t % 3;
        unsigned short* lA = &As[s][0] + w * 2048;
        unsigned short* lB = &Bs[s][0] + w * 1024;
        const unsigned short* ga = gA + (long)t * 64;
        const unsigned short* gb = gB + (long)t * 64;
        if (h == 0) {
            gl2lds16(ga,                     lA);
            gl2lds16(ga + (long)8 * ldA,     lA + 512);
            gl2lds16(gb,                     lB);
        } else {
            gl2lds16(ga + (long)16 * ldA,    lA + 1024);
            gl2lds16(ga + (long)24 * ldA,    lA + 1536);
            gl2lds16(gb + (long)8 * ldB,     lB + 512);
        }
    };

    // prologue: tiles 0 and 1 fully staged; wait tile0 (6 of 12 in flight)
    STAGE(0, 0); STAGE(0, 1);
    STAGE(1, 0); STAGE(1, 1);
    asm volatile("s_waitcnt vmcnt(6)" ::: "memory");
    __builtin_amdgcn_s_barrier();

    for (int t = 0; t < nK; ++t) {
        const int s = t % 3;
        const unsigned short* pa = &As[s][0] + mA * 64;
        const unsigned short* pb = &Bs[s][0] + nB * 64;
        bf16x8 bf0[4], bf1[4], af0[2], af1[2];

        // ---- phase A: Mfrags 0,1 ----
        if (t + 2 < nK) STAGE(t + 2, 0);
#pragma unroll
        for (int ni = 0; ni < 4; ni++) {
            bf0[ni] = *(const bf16x8*)(pb + ni * 1024 + o0);
            bf1[ni] = *(const bf16x8*)(pb + ni * 1024 + o1);
        }
        af0[0] = *(const bf16x8*)(pa + o0);
        af1[0] = *(const bf16x8*)(pa + o1);
        af0[1] = *(const bf16x8*)(pa + 1024 + o0);
        af1[1] = *(const bf16x8*)(pa + 1024 + o1);
        __builtin_amdgcn_s_barrier();
        __builtin_amdgcn_s_setprio(1);
#pragma unroll
        for (int mi = 0; mi < 2; mi++)
#pragma unroll
            for (int ni = 0; ni < 4; ni++) {
                acc[mi][ni] = __builtin_amdgcn_mfma_f32_16x16x32_bf16(
                    af0[mi], bf0[ni], acc[mi][ni], 0, 0, 0);
                acc[mi][ni] = __builtin_amdgcn_mfma_f32_16x16x32_bf16(
                    af1[mi], bf1[ni], acc[mi][ni], 0, 0, 0);
            }
        __builtin_amdgcn_s_setprio(0);
        __builtin_amdgcn_s_barrier();

        // ---- phase B: Mfrags 2,3 (reuse B frags) ----
        if (t + 2 < nK) STAGE(t + 2, 1);
        af0[0] = *(const bf16x8*)(pa + 2048 + o0);
        af1[0] = *(const bf16x8*)(pa + 2048 + o1);
        af0[1] = *(const bf16x8*)(pa + 3072 + o0);
        af1[1] = *(const bf16x8*)(pa + 3072 + o1);
        __builtin_amdgcn_s_barrier();
        __builtin_amdgcn_s_setprio(1);
#pragma unroll
        for (int mi = 0; mi < 2; mi++)
#pragma unroll
            for (int ni = 0; ni < 4; ni++) {
                acc[2 + mi][ni] = __builtin_amdgcn_mfma_f32_16x16x32_bf16(
                    af0[mi], bf0[ni], acc[2 + mi][ni], 0, 0, 0);
                acc[2 + mi][ni] = __builtin_amdgcn_mfma_f32_16x16x32_bf16(
                    af1[mi], bf1[ni], acc[2 + mi][ni], 0, 0, 0);
            }
        __builtin_amdgcn_s_setprio(0);
        // tile boundary: retire tile t+1's loads, keep t+2's 6 in flight
        if (t + 2 < nK) asm volatile("s_waitcnt vmcnt(6)" ::: "memory");
        else            asm volatile("s_waitcnt vmcnt(0)" ::: "memory");
        __builtin_amdgcn_s_barrier();
    }

    // epilogue: C/D layout col=lane&15, row=(lane>>4)*4+reg  [m89/m91]
    const int rowB = m0 + wm * 64 + q * 4;
    const int colB = n0 + wn * 64 + (l & 15);
    unsigned short* Cp = C + cOff;
#pragma unroll
    for (int mi = 0; mi < 4; mi++) {
#pragma unroll
        for (int rg = 0; rg < 4; rg++) {
            const int row = rowB + mi * 16 + rg;
            const float rs = rowScale ? rowScale[rsOff + row] : 1.0f;
#pragma unroll
            for (int ni = 0; ni < 4; ni++) {
                float v = alpha * acc[mi][ni][rg];
                if (doExp) v = __expf(v);
                Cp[(long)row * ldC + colB + ni * 16] = f2bf(v * rs);
            }
        }
    }
}

// =====================  bf16 NT GEMM (128^2, fp32-out path for out-proj)  ==========
__global__ __launch_bounds__(256) void gemm_bt_k(
    const unsigned short* __restrict__ A, const unsigned short* __restrict__ B,
    void* __restrict__ Cv, int K, int ldA, int ldB, int ldC,
    long sA1, long sA2, long sB1, long sB2, long sC1, long sC2, int d2,
    float alpha, const float* __restrict__ bias, int outBf16, int doExp,
    const float* __restrict__ rowScale, long sR1, long sR2)
{
    __shared__ unsigned short As[128 * 64];  // 16 KiB
    __shared__ unsigned short Bs[128 * 64];
    const int gx = gridDim.x, gy = gridDim.y, gz = gridDim.z;
    int bx, by, bz;
    if (((gy * gz) & 7) == 0) {
        const long L = blockIdx.x + (long)gx * (blockIdx.y + (long)gy * blockIdx.z);
        const int d = (int)(L & 7);
        const long s = L >> 3;
        bx = (int)(s % gx);
        const long yz = d + 8 * (s / gx);
        by = (int)(yz % gy);
        bz = (int)(yz / gy);
    } else {
        bx = blockIdx.x; by = blockIdx.y; bz = blockIdx.z;
    }
    const int z1 = bz / d2, z2 = bz % d2;
    A += z1 * sA1 + z2 * sA2;
    B += z1 * sB1 + z2 * sB2;
    const long cOff = z1 * sC1 + z2 * sC2;
    const long rsOff = z1 * sR1 + z2 * sR2;
    const int m0 = by * 128, n0 = bx * 128;
    const int tid = threadIdx.x;
    const int w = tid >> 6, l = tid & 63;

    const int sr = l >> 3;
    const int sq = (l & 7) ^ sr;
    const unsigned short* ga = A + (long)(m0 + w * 32 + sr) * ldA + sq * 8;
    const unsigned short* gb = B + (long)(n0 + w * 32 + sr) * ldB + sq * 8;
    unsigned short* laA = As + w * 2048;
    unsigned short* laB = Bs + w * 2048;

    const int wm = w >> 1, wn = w & 1;
    const int q = l >> 4;
    const int sl = l & 7;
    const int mA = wm * 64 + (l & 15);
    const int nB = wn * 64 + (l & 15);
    const int s0 = ((q) ^ sl) * 8;
    const int s1 = ((q + 4) ^ sl) * 8;
    const unsigned short* pa0 = As + mA * 64 + s0;
    const unsigned short* pa1 = As + mA * 64 + s1;
    const unsigned short* pb0 = Bs + nB * 64 + s0;
    const unsigned short* pb1 = Bs + nB * 64 + s1;

    f32x4 acc[4][4] = {};
    for (int kk = 0; kk < K; kk += 64) {
#pragma unroll
        for (int i = 0; i < 4; i++) {
            gl2lds16(ga + (long)i * 8 * ldA, laA + i * 512);
            gl2lds16(gb + (long)i * 8 * ldB, laB + i * 512);
        }
        ga += 64; gb += 64;
        __syncthreads();
        bf16x8 af[4], bf[4];
#pragma unroll
        for (int i = 0; i < 4; i++) {
            af[i] = *(const bf16x8*)(pa0 + i * 1024);
            bf[i] = *(const bf16x8*)(pb0 + i * 1024);
        }
#pragma unroll
        for (int mi = 0; mi < 4; mi++)
#pragma unroll
            for (int ni = 0; ni < 4; ni++)
                acc[mi][ni] = __builtin_amdgcn_mfma_f32_16x16x32_bf16(
                    af[mi], bf[ni], acc[mi][ni], 0, 0, 0);
#pragma unroll
        for (int i = 0; i < 4; i++) {
            af[i] = *(const bf16x8*)(pa1 + i * 1024);
            bf[i] = *(const bf16x8*)(pb1 + i * 1024);
        }
#pragma unroll
        for (int mi = 0; mi < 4; mi++)
#pragma unroll
            for (int ni = 0; ni < 4; ni++)
                acc[mi][ni] = __builtin_amdgcn_mfma_f32_16x16x32_bf16(
                    af[mi], bf[ni], acc[mi][ni], 0, 0, 0);
        __syncthreads();
    }

    const int rowB = m0 + wm * 64 + q * 4;
    const int colB = n0 + wn * 64 + (l & 15);
    if (outBf16) {
        unsigned short* C = (unsigned short*)Cv + cOff;
#pragma unroll
        for (int mi = 0; mi < 4; mi++) {
#pragma unroll
            for (int rg = 0; rg < 4; rg++) {
                const int row = rowB + mi * 16 + rg;
                const float rs = rowScale ? rowScale[rsOff + row] : 1.0f;
#pragma unroll
                for (int ni = 0; ni < 4; ni++) {
                    float v = alpha * acc[mi][ni][rg];
                    if (doExp) v = __expf(v);
                    C[(long)row * ldC + colB + ni * 16] = f2bf(v * rs);
                }
            }
        }
    } else {
        float* C = (float*)Cv + cOff;
#pragma unroll
        for (int ni = 0; ni < 4; ni++) {
            const int col = colB + ni * 16;
            const float bs = bias ? bias[col] : 0.f;
#pragma unroll
            for (int mi = 0; mi < 4; mi++)
#pragma unroll
                for (int rg = 0; rg < 4; rg++)
                    C[(long)(rowB + mi * 16 + rg) * ldC + col] =
                        alpha * acc[mi][ni][rg] + bs;
        }
    }
}

// ---------------- fp32 -> bf16 cast, 3 tensors in one dispatch ----------------
__global__ __launch_bounds__(256) void cvt3_k(
    const float* __restrict__ i0, const float* __restrict__ i1, const float* __restrict__ i2,
    unsigned short* __restrict__ o0, unsigned short* __restrict__ o1,
    unsigned short* __restrict__ o2, long n4)
{
    const float* in = blockIdx.z == 0 ? i0 : (blockIdx.z == 1 ? i1 : i2);
    unsigned short* out = blockIdx.z == 0 ? o0 : (blockIdx.z == 1 ? o1 : o2);
    long i = (long)blockIdx.x * 256 + threadIdx.x;
    if (i >= n4) return;
    float4 v = ((const float4*)in)[i];
    ushort4 o;
    o.x = f2bf(v.x); o.y = f2bf(v.y); o.z = f2bf(v.z); o.w = f2bf(v.w);
    ((ushort4*)out)[i] = o;
}

// ------- transpose + cast, 3 tensors x 8 heads in one dispatch -------
__global__ __launch_bounds__(256) void transcvt3_k(
    const float* __restrict__ i0, const float* __restrict__ i1, const float* __restrict__ i2,
    unsigned short* __restrict__ o0, unsigned short* __restrict__ o1,
    unsigned short* __restrict__ o2)
{
    __shared__ float t[32][33];
    const int zt = blockIdx.z >> 3, h = blockIdx.z & 7;
    const float* in = (zt == 0 ? i0 : (zt == 1 ? i1 : i2)) + (long)h * D_ * D_;
    unsigned short* out = (zt == 0 ? o0 : (zt == 1 ? o1 : o2)) + (long)h * D_ * D_;
    const int r0 = blockIdx.y * 32, c0 = blockIdx.x * 32;
    const int tr = threadIdx.x >> 5, tc = threadIdx.x & 31;
#pragma unroll
    for (int i = 0; i < 4; i++)
        t[tr + i * 8][tc] = in[(long)(r0 + tr + i * 8) * D_ + c0 + tc];
    __syncthreads();
#pragma unroll
    for (int i = 0; i < 4; i++)
        out[(long)(c0 + tr + i * 8) * D_ + r0 + tc] = f2bf(t[tc][tr + i * 8]);
}

// ---------------- transpose + cast: in [R,C] fp32 -> out [C,R] bf16 ----------------
__global__ __launch_bounds__(256) void transcvt_k(
    const float* __restrict__ in, unsigned short* __restrict__ out, int R, int C)
{
    __shared__ float t[32][33];
    const int r0 = blockIdx.y * 32, c0 = blockIdx.x * 32;
    const int tr = threadIdx.x >> 5, tc = threadIdx.x & 31;
#pragma unroll
    for (int i = 0; i < 4; i++)
        t[tr + i * 8][tc] = in[(long)(r0 + tr + i * 8) * C + c0 + tc];
    __syncthreads();
#pragma unroll
    for (int i = 0; i < 4; i++)
        out[(long)(c0 + tr + i * 8) * R + r0 + tc] = f2bf(t[tc][tr + i * 8]);
}

// ------- row-sums of E (8 heads) + 1/l + attn_avg = sum_h e/(H*l) -------
__device__ inline float wred_sum(float v) {
#pragma unroll
    for (int o = 32; o; o >>= 1) v += __shfl_down(v, o);
    return v;
}
__global__ __launch_bounds__(256) void sumavg_k(
    const unsigned short* __restrict__ E, float* __restrict__ avg,
    float* __restrict__ linv)
{
    const int blk = blockIdx.x;            // b*SS + s
    const int b = blk >> 11, s = blk & (SS - 1);
    const int tid = threadIdx.x;
    __shared__ float red[4];
    float av[8] = {};
    const int t0 = tid * 8;                // thread owns 8 contiguous cols
    for (int h = 0; h < H_; h++) {
        const long rowOff = ((long)(h * BB + b) * SS + s) * SS + t0;
        const ushort4 u0 = *(const ushort4*)(E + rowOff);
        const ushort4 u1 = *(const ushort4*)(E + rowOff + 4);
        float vals[8] = {bf2f(u0.x), bf2f(u0.y), bf2f(u0.z), bf2f(u0.w),
                         bf2f(u1.x), bf2f(u1.y), bf2f(u1.z), bf2f(u1.w)};
        float sum = 0.f;
#pragma unroll
        for (int i = 0; i < 8; i++) sum += vals[i];
        float wsum = wred_sum(sum);
        if ((tid & 63) == 0) red[tid >> 6] = wsum;
        __syncthreads();
        sum = red[0] + red[1] + red[2] + red[3];
        __syncthreads();
        const float inv = 1.0f / sum;
        if (tid == 0) linv[(long)(h * BB + b) * SS + s] = inv;
        const float invH = inv * 0.125f;
#pragma unroll
        for (int i = 0; i < 8; i++) av[i] += vals[i] * invH;
    }
    const long aOff = ((long)b * SS + s) * SS + t0;
    float4 a0 = {av[0], av[1], av[2], av[3]};
    float4 a1 = {av[4], av[5], av[6], av[7]};
    *(float4*)(avg + aOff) = a0;
    *(float4*)(avg + aOff + 4) = a1;
}

// ---------------- out = part0 + part1 + bias (out-proj K-split combine) ----------------
__global__ __launch_bounds__(256) void addbias_k(
    const float* __restrict__ p0, const float* __restrict__ p1,
    const float* __restrict__ bz, float* __restrict__ out)
{
    const long n4 = (long)MS * D_ / 4;
    long i = (long)blockIdx.x * 256 + threadIdx.x;
    if (i >= n4) return;
    const int col4 = (int)((i * 4) & (D_ - 1));
    float4 a = ((const float4*)p0)[i];
    float4 b = ((const float4*)p1)[i];
    float4 c = *(const float4*)(bz + col4);
    float4 o = {a.x + b.x + c.x, a.y + b.y + c.y, a.z + b.z + c.z, a.w + b.w + c.w};
    ((float4*)out)[i] = o;
}

// ---------------- host launch ----------------
extern "C" void kernel_launch(void* const* d_in, const int* in_sizes, int n_in,
                              void* d_out, int out_size, void* d_ws, size_t ws_size,
                              hipStream_t stream)
{
    const float* Xq = (const float*)d_in[0];
    const float* Xk = (const float*)d_in[1];
    const float* Xv = (const float*)d_in[2];
    const float* Wq = (const float*)d_in[3];
    const float* Wk = (const float*)d_in[4];
    const float* Wv = (const float*)d_in[5];
    const float* Wz = (const float*)d_in[6];
    const float* bz = (const float*)d_in[7];

    float* out      = (float*)d_out;             // [B,S,D]
    float* attn_avg = out + (long)MS * D_;       // [B,S,S]

    unsigned char* ws = nullptr;
    (void)hipGetSymbolAddress((void**)&ws, HIP_SYMBOL(g_ws));
    unsigned short* Xbq = (unsigned short*)(ws + OFF_XQ);
    unsigned short* Xbk = (unsigned short*)(ws + OFF_XK);
    unsigned short* Xbv = (unsigned short*)(ws + OFF_XV);
    unsigned short* Wqt = (unsigned short*)(ws + OFF_WQT);
    unsigned short* Wkt = (unsigned short*)(ws + OFF_WKT);
    unsigned short* Wvt = (unsigned short*)(ws + OFF_WVT);
    unsigned short* Wzt = (unsigned short*)(ws + OFF_WZT);
    unsigned short* qb  = (unsigned short*)(ws + OFF_QB);   // [h][b*s][e]
    unsigned short* vT  = (unsigned short*)(ws + OFF_VT);   // [h][b][e][t]
    unsigned short* scb = (unsigned short*)(ws + OFF_SC);   // [h][b][s][t] E=exp(scores)
    unsigned short* zal = (unsigned short*)(ws + OFF_Z);    // [b*s][h*e]
    float*          opp = (float*)(ws + OFF_OP);            // 2x [b*s][f] partials
    float*          linv = (float*)(ws + OFF_LV);           // [h][b][s] 1/rowsum

    const float inv4 = 1.0f / powf((float)D_, 0.25f);

    // 1) casts + weight transposes
    const long n4x = (long)MS * D_ / 4;
    cvt3_k<<<dim3((n4x + 255) / 256, 1, 3), 256, 0, stream>>>(
        Xq, Xk, Xv, Xbq, Xbk, Xbv, n4x);
    transcvt3_k<<<dim3(16, 16, 24), 256, 0, stream>>>(Wq, Wk, Wv, Wqt, Wkt, Wvt);
    transcvt_k<<<dim3(16, 128, 1), 256, 0, stream>>>(Wz, Wzt, HD, D_);

    // 2) q & k projections in ONE dispatch (z1: q/k, z2: head), scaled by inv4
    gemm256_k<<<dim3(4, 16, 16), 512, 0, stream>>>(
        Xbq, Wqt, qb, D_, D_, D_, D_,
        (long)MS * D_, 0, (long)H_ * D_ * D_, (long)D_ * D_,
        (long)H_ * MS * D_, (long)MS * D_, 8, inv4, 0, nullptr, 0, 0);
    // v^T[e][t] = sum_d Wvt[e][d] * Xv[t][d]  (z=(h,b), d2=2)
    gemm256_k<<<dim3(16, 2, 16), 512, 0, stream>>>(
        Wvt, Xbv, vT, D_, D_, D_, SS,
        (long)D_ * D_, 0, 0, (long)SS * D_, (long)2 * D_ * SS, (long)D_ * SS, 2,
        1.0f, 0, nullptr, 0, 0);

    // 3) E = exp(q·k) -> bf16, batched over (h,b). No max-subtraction needed:
    //    logits ~N(0,1), |logit| < ~7, exp safe in fp32/bf16.
    gemm256_k<<<dim3(16, 8, 16), 512, 0, stream>>>(
        qb, qb + (long)H_ * MS * D_, scb, D_, D_, D_, SS,
        (long)MS * D_, (long)SS * D_, (long)MS * D_, (long)SS * D_,
        (long)2 * SS * SS, (long)SS * SS, 2, 1.0f, 1, nullptr, 0, 0);

    // 4) row sums + 1/l + attn_avg (E read once; no probs write-back)
    sumavg_k<<<dim3(BB * SS), 256, 0, stream>>>(scb, attn_avg, linv);

    // 5) PV: z[s][e] = (1/l_s) * sum_t E[s,t]*vT[e,t] -> zal[b*s][h*e]
    //    (normalization folded into epilogue via rowScale=linv)
    gemm256_k<<<dim3(4, 8, 16), 512, 0, stream>>>(
        scb, vT, zal, SS, SS, SS, HD,
        (long)2 * SS * SS, (long)SS * SS, (long)2 * D_ * SS, (long)D_ * SS,
        512, (long)SS * HD, 2, 1.0f, 0,
        linv, (long)BB * SS, (long)SS);

    // 6) out-proj, K-split=2 (z2 halves of he): partials -> combine with bias
    gemm_bt_k<<<dim3(4, 32, 2), 256, 0, stream>>>(
        zal, Wzt, opp, HD / 2, HD, HD, D_,
        0, 2048, 0, 2048, 0, (long)MS * D_, 2, 1.0f, nullptr, 0, 0, nullptr, 0, 0);
    const long n4o = (long)MS * D_ / 4;
    addbias_k<<<dim3((n4o + 255) / 256), 256, 0, stream>>>(
        opp, opp + (long)MS * D_, bz, out);
}

// Round 2
// 476.098 us; speedup vs baseline: 1.2998x; 1.2998x over previous
//
#include <hip/hip_runtime.h>
#include <math.h>

// Problem constants: B=2, S=2048, D=512, H=8
#define BB 2
#define SS 2048
#define D_ 512
#define H_ 8
#define MS (BB * SS)   // 4096 rows (b,s)
#define HD (H_ * D_)   // 4096 concat dim

typedef short bf16x8 __attribute__((ext_vector_type(8)));
typedef float f32x4 __attribute__((ext_vector_type(4)));

// ---- bf16 helpers (RNE) ----
__device__ inline unsigned short f2bf(float f) {
    union { float f; unsigned u; } x{f};
    unsigned r = x.u + 0x7fff + ((x.u >> 16) & 1);
    return (unsigned short)(r >> 16);
}
__device__ inline float bf2f(unsigned short u) {
    union { unsigned u; float f; } x{(unsigned)u << 16};
    return x.f;
}

// ---- static workspace ----
constexpr size_t SZ_X   = (size_t)MS * D_ * 2;           // 4 MiB per X (bf16)
constexpr size_t SZ_W   = (size_t)H_ * D_ * D_ * 2;      // 4 MiB per W^T
constexpr size_t SZ_WZ  = (size_t)HD * D_ * 2;           // 4 MiB Wz^T
constexpr size_t SZ_QK  = (size_t)H_ * MS * D_ * 2;      // 32 MiB q or k
constexpr size_t SZ_SC  = (size_t)H_ * BB * SS * SS * 2; // 128 MiB E = exp(scores) bf16
constexpr size_t SZ_Z   = (size_t)MS * HD * 2;           // 32 MiB z concat
constexpr size_t SZ_OP  = (size_t)2 * MS * D_ * 4;       // 16 MiB out-proj K-split partials
constexpr size_t SZ_LV  = (size_t)H_ * BB * SS * 4;      // 128 KiB 1/rowsum
constexpr size_t OFF_XQ  = 0;
constexpr size_t OFF_XK  = OFF_XQ + SZ_X;
constexpr size_t OFF_XV  = OFF_XK + SZ_X;
constexpr size_t OFF_WQT = OFF_XV + SZ_X;
constexpr size_t OFF_WKT = OFF_WQT + SZ_W;
constexpr size_t OFF_WVT = OFF_WKT + SZ_W;
constexpr size_t OFF_WZT = OFF_WVT + SZ_W;
constexpr size_t OFF_QB  = OFF_WZT + SZ_WZ;
constexpr size_t OFF_KB  = OFF_QB + SZ_QK;
constexpr size_t OFF_VT  = OFF_KB + SZ_QK;
constexpr size_t OFF_SC  = OFF_VT + SZ_QK;
constexpr size_t OFF_Z   = OFF_SC + SZ_SC;
constexpr size_t OFF_OP  = OFF_Z + SZ_Z;
constexpr size_t OFF_LV  = OFF_OP + SZ_OP;
constexpr size_t WS_TOTAL = OFF_LV + SZ_LV;
__device__ __align__(256) unsigned char g_ws[WS_TOTAL];

// ---- async global->LDS, 16 B/lane; LDS dest = wave-uniform base + lane*16 ----
__device__ inline void gl2lds16(const unsigned short* g, unsigned short* l) {
    __builtin_amdgcn_global_load_lds(
        (const __attribute__((address_space(1))) void*)g,
        (__attribute__((address_space(3))) void*)l, 16, 0, 0);
}

#define BAR() __builtin_amdgcn_s_barrier()
#define PRIO1() __builtin_amdgcn_s_setprio(1)
#define PRIO0() __builtin_amdgcn_s_setprio(0)
#define VMW4() asm volatile("s_waitcnt vmcnt(4)" ::: "memory")
#define VMW0() asm volatile("s_waitcnt vmcnt(0)" ::: "memory")

// ---- fragment helpers (all call sites pass literal qm/qn -> static indices) ----
__device__ __forceinline__ void rd_a(const unsigned short* p, int qm, int o0, int o1,
                                     bf16x8 (&Af)[8]) {
#pragma unroll
    for (int fi = 0; fi < 4; fi++) {
        Af[2 * fi]     = *(const bf16x8*)(p + (qm * 64 + fi * 16) * 64 + o0);
        Af[2 * fi + 1] = *(const bf16x8*)(p + (qm * 64 + fi * 16) * 64 + o1);
    }
}
__device__ __forceinline__ void rd_b(const unsigned short* p, int qn, int o0, int o1,
                                     bf16x8 (&Bf)[4]) {
#pragma unroll
    for (int fj = 0; fj < 2; fj++) {
        Bf[2 * fj]     = *(const bf16x8*)(p + (qn * 32 + fj * 16) * 64 + o0);
        Bf[2 * fj + 1] = *(const bf16x8*)(p + (qn * 32 + fj * 16) * 64 + o1);
    }
}
__device__ __forceinline__ void mma_q(int qm, int qn, const bf16x8 (&Af)[8],
                                      const bf16x8 (&Bf)[4], f32x4 (&acc)[8][4]) {
#pragma unroll
    for (int fi = 0; fi < 4; fi++)
#pragma unroll
        for (int fj = 0; fj < 2; fj++) {
            acc[qm * 4 + fi][qn * 2 + fj] = __builtin_amdgcn_mfma_f32_16x16x32_bf16(
                Af[2 * fi], Bf[2 * fj], acc[qm * 4 + fi][qn * 2 + fj], 0, 0, 0);
            acc[qm * 4 + fi][qn * 2 + fj] = __builtin_amdgcn_mfma_f32_16x16x32_bf16(
                Af[2 * fi + 1], Bf[2 * fj + 1], acc[qm * 4 + fi][qn * 2 + fj], 0, 0, 0);
        }
}

// ================  256x256 8-phase pipelined bf16 NT GEMM (m201 template)  ================
// C = f(alpha * A @ B'^T), A [M,K] bf16 K-contig, B' [N,K] bf16 K-contig, out bf16.
// BM=BN=256, BK=64. 8 waves 2Mx4N, per-wave 128x64 out (acc 8x4 f32x4 = 128 VGPR).
// LDS 128 KiB: 2 dbuf x (A 256x64 + B 256x64). Iter u computes tiles t0=2u (buf0,
// phases P1-P4) and t1=2u+1 (buf1, P5-P8). Per phase: {ds_read quadrant frags
// (12/4/8/0, A+B frag reuse); stage one 128-row half-tile (2x gl2lds); barrier;
// setprio(1); 16 MFMA (one 64x32 C-quadrant x K=64); setprio(0); barrier}.
// Staging: P1,P2 = A-halves(t1)->buf1; P3..P6 = Bh0,Bh1,Ah0,Ah1(t0+2)->buf0;
// P7,P8 = B-halves(t0+3)->buf1.  vmcnt(4) ONLY at end of P4 and P8 (never 0
// mid-loop): at each, 12 outstanding -> retires exactly the 8 the next 4 phases
// consume; invariant: 4 in flight (next tile-pair's B halves) across barriers.
// Overwrite safety: each region staged >=2 barriers after its last ds_read.
// LDS rows of 64 shorts, quad j of row r at slot j^(r&7) (pre-swizzled global
// source) -> ds_read_b128 conflict-free (verified 0 in production).
__global__ __launch_bounds__(512, 2) void gemm256_k(
    const unsigned short* __restrict__ A, const unsigned short* __restrict__ B,
    unsigned short* __restrict__ C, int K, int ldA, int ldB, int ldC,
    long sA1, long sA2, long sB1, long sB2, long sC1, long sC2, int d2,
    float alpha, int doExp, const float* __restrict__ rowScale, long sR1, long sR2)
{
    __shared__ unsigned short LA[2][256 * 64];   // 2 x 32 KiB
    __shared__ unsigned short LB[2][256 * 64];   // 2 x 32 KiB
    // XCD-aware block swizzle (all grids have (gy*gz)%8==0)
    const int gx = gridDim.x, gy = gridDim.y, gz = gridDim.z;
    int bx, by, bz;
    if (((gy * gz) & 7) == 0) {
        const long L = blockIdx.x + (long)gx * (blockIdx.y + (long)gy * blockIdx.z);
        const int d = (int)(L & 7);
        const long s = L >> 3;
        bx = (int)(s % gx);
        const long yz = d + 8 * (s / gx);
        by = (int)(yz % gy);
        bz = (int)(yz / gy);
    } else {
        bx = blockIdx.x; by = blockIdx.y; bz = blockIdx.z;
    }
    const int z1 = bz / d2, z2 = bz % d2;
    A += z1 * sA1 + z2 * sA2;
    B += z1 * sB1 + z2 * sB2;
    const long cOff = z1 * sC1 + z2 * sC2;
    const long rsOff = z1 * sR1 + z2 * sR2;
    const int m0 = by * 256, n0 = bx * 256;
    const int tid = threadIdx.x;
    const int w = tid >> 6, l = tid & 63;
    const int wm = w >> 2, wn = w & 3;          // 2M x 4N waves

    // staging: wave w owns 16 rows (w*16..+16) of each 128-row half-tile
    const int sr = l >> 3;
    const int sq = (l & 7) ^ sr;                 // pre-swizzled global quad
    const unsigned short* gA = A + (long)(m0 + w * 16 + sr) * ldA + sq * 8;
    const unsigned short* gB = B + (long)(n0 + w * 16 + sr) * ldB + sq * 8;

    // fragment read bases
    const int q = l >> 4, sl = l & 7;
    const int o0 = (q ^ sl) * 8;
    const int o1 = ((q + 4) ^ sl) * 8;
    const unsigned short* pa0 = &LA[0][(wm * 128 + (l & 15)) * 64];
    const unsigned short* pa1 = &LA[1][(wm * 128 + (l & 15)) * 64];
    const unsigned short* pb0 = &LB[0][(wn * 64 + (l & 15)) * 64];
    const unsigned short* pb1 = &LB[1][(wn * 64 + (l & 15)) * 64];

    const int nK2 = K >> 7;                      // K-tile pairs (K % 128 == 0)
    f32x4 acc[8][4] = {};
    bf16x8 Af[8], Bf0[4], Bf1[4];

#define STG_A(bufi, half, t) do { \
    gl2lds16(gA + (long)((half) * 128) * ldA + (long)(t) * 64, \
             &LA[bufi][((half) * 128 + w * 16) * 64]); \
    gl2lds16(gA + (long)((half) * 128 + 8) * ldA + (long)(t) * 64, \
             &LA[bufi][((half) * 128 + w * 16 + 8) * 64]); } while (0)
#define STG_B(bufi, half, t) do { \
    gl2lds16(gB + (long)((half) * 128) * ldB + (long)(t) * 64, \
             &LB[bufi][((half) * 128 + w * 16) * 64]); \
    gl2lds16(gB + (long)((half) * 128 + 8) * ldB + (long)(t) * 64, \
             &LB[bufi][((half) * 128 + w * 16 + 8) * 64]); } while (0)

    // prologue: tile0 fully (8 loads) + tile1 B-halves (4) -> vmcnt(4) keeps
    // t1-B in flight, retires tile0.
    STG_A(0, 0, 0); STG_A(0, 1, 0);
    STG_B(0, 0, 0); STG_B(0, 1, 0);
    STG_B(1, 0, 1); STG_B(1, 1, 1);
    VMW4();
    BAR();

    for (int u = 0; u < nK2; ++u) {
        const int t1 = 2 * u + 1, t2 = 2 * u + 2, t3 = 2 * u + 3;
        const bool have = (u + 1 < nK2);
        // ---- P1: tile t0 (buf0) quadrant (0,0) ----
        rd_a(pa0, 0, o0, o1, Af);
        rd_b(pb0, 0, o0, o1, Bf0);
        STG_A(1, 0, t1);
        BAR(); PRIO1(); mma_q(0, 0, Af, Bf0, acc); PRIO0(); BAR();
        // ---- P2: quadrant (0,1) ----
        rd_b(pb0, 1, o0, o1, Bf1);
        STG_A(1, 1, t1);
        BAR(); PRIO1(); mma_q(0, 1, Af, Bf1, acc); PRIO0(); BAR();
        // ---- P3: quadrant (1,1) ----
        rd_a(pa0, 1, o0, o1, Af);
        if (have) STG_B(0, 0, t2);
        BAR(); PRIO1(); mma_q(1, 1, Af, Bf1, acc); PRIO0(); BAR();
        // ---- P4: quadrant (1,0), no reads ----
        if (have) STG_B(0, 1, t2);
        BAR(); PRIO1(); mma_q(1, 0, Af, Bf0, acc); PRIO0();
        if (have) VMW4(); else VMW0();
        BAR();
        // ---- P5: tile t1 (buf1) quadrant (0,0) ----
        rd_a(pa1, 0, o0, o1, Af);
        rd_b(pb1, 0, o0, o1, Bf0);
        if (have) STG_A(0, 0, t2);
        BAR(); PRIO1(); mma_q(0, 0, Af, Bf0, acc); PRIO0(); BAR();
        // ---- P6: quadrant (0,1) ----
        rd_b(pb1, 1, o0, o1, Bf1);
        if (have) STG_A(0, 1, t2);
        BAR(); PRIO1(); mma_q(0, 1, Af, Bf1, acc); PRIO0(); BAR();
        // ---- P7: quadrant (1,1) ----
        rd_a(pa1, 1, o0, o1, Af);
        if (have) STG_B(1, 0, t3);
        BAR(); PRIO1(); mma_q(1, 1, Af, Bf1, acc); PRIO0(); BAR();
        // ---- P8: quadrant (1,0) ----
        if (have) STG_B(1, 1, t3);
        BAR(); PRIO1(); mma_q(1, 0, Af, Bf0, acc); PRIO0();
        if (have) VMW4(); else VMW0();
        BAR();
    }
#undef STG_A
#undef STG_B

    // epilogue: C/D layout col=lane&15, row=(lane>>4)*4+reg  [m89/m91]
    const int rowB = m0 + wm * 128 + q * 4;
    const int colB = n0 + wn * 64 + (l & 15);
    unsigned short* Cp = C + cOff;
#pragma unroll
    for (int mi = 0; mi < 8; mi++) {
#pragma unroll
        for (int rg = 0; rg < 4; rg++) {
            const int row = rowB + mi * 16 + rg;
            const float rs = rowScale ? rowScale[rsOff + row] : 1.0f;
#pragma unroll
            for (int nj = 0; nj < 4; nj++) {
                float v = alpha * acc[mi][nj][rg];
                if (doExp) v = __expf(v);
                Cp[(long)row * ldC + colB + nj * 16] = f2bf(v * rs);
            }
        }
    }
}

// =====================  bf16 NT GEMM (128^2, fp32-out path for out-proj)  ==========
__global__ __launch_bounds__(256) void gemm_bt_k(
    const unsigned short* __restrict__ A, const unsigned short* __restrict__ B,
    void* __restrict__ Cv, int K, int ldA, int ldB, int ldC,
    long sA1, long sA2, long sB1, long sB2, long sC1, long sC2, int d2,
    float alpha, const float* __restrict__ bias, int outBf16, int doExp,
    const float* __restrict__ rowScale, long sR1, long sR2)
{
    __shared__ unsigned short As[128 * 64];  // 16 KiB
    __shared__ unsigned short Bs[128 * 64];
    const int gx = gridDim.x, gy = gridDim.y, gz = gridDim.z;
    int bx, by, bz;
    if (((gy * gz) & 7) == 0) {
        const long L = blockIdx.x + (long)gx * (blockIdx.y + (long)gy * blockIdx.z);
        const int d = (int)(L & 7);
        const long s = L >> 3;
        bx = (int)(s % gx);
        const long yz = d + 8 * (s / gx);
        by = (int)(yz % gy);
        bz = (int)(yz / gy);
    } else {
        bx = blockIdx.x; by = blockIdx.y; bz = blockIdx.z;
    }
    const int z1 = bz / d2, z2 = bz % d2;
    A += z1 * sA1 + z2 * sA2;
    B += z1 * sB1 + z2 * sB2;
    const long cOff = z1 * sC1 + z2 * sC2;
    const long rsOff = z1 * sR1 + z2 * sR2;
    const int m0 = by * 128, n0 = bx * 128;
    const int tid = threadIdx.x;
    const int w = tid >> 6, l = tid & 63;

    const int sr = l >> 3;
    const int sq = (l & 7) ^ sr;
    const unsigned short* ga = A + (long)(m0 + w * 32 + sr) * ldA + sq * 8;
    const unsigned short* gb = B + (long)(n0 + w * 32 + sr) * ldB + sq * 8;
    unsigned short* laA = As + w * 2048;
    unsigned short* laB = Bs + w * 2048;

    const int wm = w >> 1, wn = w & 1;
    const int q = l >> 4;
    const int sl = l & 7;
    const int mA = wm * 64 + (l & 15);
    const int nB = wn * 64 + (l & 15);
    const int s0 = ((q) ^ sl) * 8;
    const int s1 = ((q + 4) ^ sl) * 8;
    const unsigned short* pa0 = As + mA * 64 + s0;
    const unsigned short* pa1 = As + mA * 64 + s1;
    const unsigned short* pb0 = Bs + nB * 64 + s0;
    const unsigned short* pb1 = Bs + nB * 64 + s1;

    f32x4 acc[4][4] = {};
    for (int kk = 0; kk < K; kk += 64) {
#pragma unroll
        for (int i = 0; i < 4; i++) {
            gl2lds16(ga + (long)i * 8 * ldA, laA + i * 512);
            gl2lds16(gb + (long)i * 8 * ldB, laB + i * 512);
        }
        ga += 64; gb += 64;
        __syncthreads();
        bf16x8 af[4], bf[4];
#pragma unroll
        for (int i = 0; i < 4; i++) {
            af[i] = *(const bf16x8*)(pa0 + i * 1024);
            bf[i] = *(const bf16x8*)(pb0 + i * 1024);
        }
#pragma unroll
        for (int mi = 0; mi < 4; mi++)
#pragma unroll
            for (int ni = 0; ni < 4; ni++)
                acc[mi][ni] = __builtin_amdgcn_mfma_f32_16x16x32_bf16(
                    af[mi], bf[ni], acc[mi][ni], 0, 0, 0);
#pragma unroll
        for (int i = 0; i < 4; i++) {
            af[i] = *(const bf16x8*)(pa1 + i * 1024);
            bf[i] = *(const bf16x8*)(pb1 + i * 1024);
        }
#pragma unroll
        for (int mi = 0; mi < 4; mi++)
#pragma unroll
            for (int ni = 0; ni < 4; ni++)
                acc[mi][ni] = __builtin_amdgcn_mfma_f32_16x16x32_bf16(
                    af[mi], bf[ni], acc[mi][ni], 0, 0, 0);
        __syncthreads();
    }

    const int rowB = m0 + wm * 64 + q * 4;
    const int colB = n0 + wn * 64 + (l & 15);
    if (outBf16) {
        unsigned short* C = (unsigned short*)Cv + cOff;
#pragma unroll
        for (int mi = 0; mi < 4; mi++) {
#pragma unroll
            for (int rg = 0; rg < 4; rg++) {
                const int row = rowB + mi * 16 + rg;
                const float rs = rowScale ? rowScale[rsOff + row] : 1.0f;
#pragma unroll
                for (int ni = 0; ni < 4; ni++) {
                    float v = alpha * acc[mi][ni][rg];
                    if (doExp) v = __expf(v);
                    C[(long)row * ldC + colB + ni * 16] = f2bf(v * rs);
                }
            }
        }
    } else {
        float* C = (float*)Cv + cOff;
#pragma unroll
        for (int ni = 0; ni < 4; ni++) {
            const int col = colB + ni * 16;
            const float bs = bias ? bias[col] : 0.f;
#pragma unroll
            for (int mi = 0; mi < 4; mi++)
#pragma unroll
                for (int rg = 0; rg < 4; rg++)
                    C[(long)(rowB + mi * 16 + rg) * ldC + col] =
                        alpha * acc[mi][ni][rg] + bs;
        }
    }
}

// ---------------- fp32 -> bf16 cast, 3 tensors in one dispatch ----------------
__global__ __launch_bounds__(256) void cvt3_k(
    const float* __restrict__ i0, const float* __restrict__ i1, const float* __restrict__ i2,
    unsigned short* __restrict__ o0, unsigned short* __restrict__ o1,
    unsigned short* __restrict__ o2, long n4)
{
    const float* in = blockIdx.z == 0 ? i0 : (blockIdx.z == 1 ? i1 : i2);
    unsigned short* out = blockIdx.z == 0 ? o0 : (blockIdx.z == 1 ? o1 : o2);
    long i = (long)blockIdx.x * 256 + threadIdx.x;
    if (i >= n4) return;
    float4 v = ((const float4*)in)[i];
    ushort4 o;
    o.x = f2bf(v.x); o.y = f2bf(v.y); o.z = f2bf(v.z); o.w = f2bf(v.w);
    ((ushort4*)out)[i] = o;
}

// ------- transpose + cast, 3 tensors x 8 heads in one dispatch -------
__global__ __launch_bounds__(256) void transcvt3_k(
    const float* __restrict__ i0, const float* __restrict__ i1, const float* __restrict__ i2,
    unsigned short* __restrict__ o0, unsigned short* __restrict__ o1,
    unsigned short* __restrict__ o2)
{
    __shared__ float t[32][33];
    const int zt = blockIdx.z >> 3, h = blockIdx.z & 7;
    const float* in = (zt == 0 ? i0 : (zt == 1 ? i1 : i2)) + (long)h * D_ * D_;
    unsigned short* out = (zt == 0 ? o0 : (zt == 1 ? o1 : o2)) + (long)h * D_ * D_;
    const int r0 = blockIdx.y * 32, c0 = blockIdx.x * 32;
    const int tr = threadIdx.x >> 5, tc = threadIdx.x & 31;
#pragma unroll
    for (int i = 0; i < 4; i++)
        t[tr + i * 8][tc] = in[(long)(r0 + tr + i * 8) * D_ + c0 + tc];
    __syncthreads();
#pragma unroll
    for (int i = 0; i < 4; i++)
        out[(long)(c0 + tr + i * 8) * D_ + r0 + tc] = f2bf(t[tc][tr + i * 8]);
}

// ---------------- transpose + cast: in [R,C] fp32 -> out [C,R] bf16 ----------------
__global__ __launch_bounds__(256) void transcvt_k(
    const float* __restrict__ in, unsigned short* __restrict__ out, int R, int C)
{
    __shared__ float t[32][33];
    const int r0 = blockIdx.y * 32, c0 = blockIdx.x * 32;
    const int tr = threadIdx.x >> 5, tc = threadIdx.x & 31;
#pragma unroll
    for (int i = 0; i < 4; i++)
        t[tr + i * 8][tc] = in[(long)(r0 + tr + i * 8) * C + c0 + tc];
    __syncthreads();
#pragma unroll
    for (int i = 0; i < 4; i++)
        out[(long)(c0 + tr + i * 8) * R + r0 + tc] = f2bf(t[tc][tr + i * 8]);
}

// ------- row-sums of E (8 heads) + 1/l + attn_avg = sum_h e/(H*l) -------
__device__ inline float wred_sum(float v) {
#pragma unroll
    for (int o = 32; o; o >>= 1) v += __shfl_down(v, o);
    return v;
}
__global__ __launch_bounds__(256) void sumavg_k(
    const unsigned short* __restrict__ E, float* __restrict__ avg,
    float* __restrict__ linv)
{
    const int blk = blockIdx.x;            // b*SS + s
    const int b = blk >> 11, s = blk & (SS - 1);
    const int tid = threadIdx.x;
    __shared__ float red[4];
    float av[8] = {};
    const int t0 = tid * 8;                // thread owns 8 contiguous cols
    for (int h = 0; h < H_; h++) {
        const long rowOff = ((long)(h * BB + b) * SS + s) * SS + t0;
        const ushort4 u0 = *(const ushort4*)(E + rowOff);
        const ushort4 u1 = *(const ushort4*)(E + rowOff + 4);
        float vals[8] = {bf2f(u0.x), bf2f(u0.y), bf2f(u0.z), bf2f(u0.w),
                         bf2f(u1.x), bf2f(u1.y), bf2f(u1.z), bf2f(u1.w)};
        float sum = 0.f;
#pragma unroll
        for (int i = 0; i < 8; i++) sum += vals[i];
        float wsum = wred_sum(sum);
        if ((tid & 63) == 0) red[tid >> 6] = wsum;
        __syncthreads();
        sum = red[0] + red[1] + red[2] + red[3];
        __syncthreads();
        const float inv = 1.0f / sum;
        if (tid == 0) linv[(long)(h * BB + b) * SS + s] = inv;
        const float invH = inv * 0.125f;
#pragma unroll
        for (int i = 0; i < 8; i++) av[i] += vals[i] * invH;
    }
    const long aOff = ((long)b * SS + s) * SS + t0;
    float4 a0 = {av[0], av[1], av[2], av[3]};
    float4 a1 = {av[4], av[5], av[6], av[7]};
    *(float4*)(avg + aOff) = a0;
    *(float4*)(avg + aOff + 4) = a1;
}

// ---------------- out = part0 + part1 + bias (out-proj K-split combine) ----------------
__global__ __launch_bounds__(256) void addbias_k(
    const float* __restrict__ p0, const float* __restrict__ p1,
    const float* __restrict__ bz, float* __restrict__ out)
{
    const long n4 = (long)MS * D_ / 4;
    long i = (long)blockIdx.x * 256 + threadIdx.x;
    if (i >= n4) return;
    const int col4 = (int)((i * 4) & (D_ - 1));
    float4 a = ((const float4*)p0)[i];
    float4 b = ((const float4*)p1)[i];
    float4 c = *(const float4*)(bz + col4);
    float4 o = {a.x + b.x + c.x, a.y + b.y + c.y, a.z + b.z + c.z, a.w + b.w + c.w};
    ((float4*)out)[i] = o;
}

// ---------------- host launch ----------------
extern "C" void kernel_launch(void* const* d_in, const int* in_sizes, int n_in,
                              void* d_out, int out_size, void* d_ws, size_t ws_size,
                              hipStream_t stream)
{
    const float* Xq = (const float*)d_in[0];
    const float* Xk = (const float*)d_in[1];
    const float* Xv = (const float*)d_in[2];
    const float* Wq = (const float*)d_in[3];
    const float* Wk = (const float*)d_in[4];
    const float* Wv = (const float*)d_in[5];
    const float* Wz = (const float*)d_in[6];
    const float* bz = (const float*)d_in[7];

    float* out      = (float*)d_out;             // [B,S,D]
    float* attn_avg = out + (long)MS * D_;       // [B,S,S]

    unsigned char* ws = nullptr;
    (void)hipGetSymbolAddress((void**)&ws, HIP_SYMBOL(g_ws));
    unsigned short* Xbq = (unsigned short*)(ws + OFF_XQ);
    unsigned short* Xbk = (unsigned short*)(ws + OFF_XK);
    unsigned short* Xbv = (unsigned short*)(ws + OFF_XV);
    unsigned short* Wqt = (unsigned short*)(ws + OFF_WQT);
    unsigned short* Wkt = (unsigned short*)(ws + OFF_WKT);
    unsigned short* Wvt = (unsigned short*)(ws + OFF_WVT);
    unsigned short* Wzt = (unsigned short*)(ws + OFF_WZT);
    unsigned short* qb  = (unsigned short*)(ws + OFF_QB);   // [h][b*s][e]
    unsigned short* vT  = (unsigned short*)(ws + OFF_VT);   // [h][b][e][t]
    unsigned short* scb = (unsigned short*)(ws + OFF_SC);   // [h][b][s][t] E=exp(scores)
    unsigned short* zal = (unsigned short*)(ws + OFF_Z);    // [b*s][h*e]
    float*          opp = (float*)(ws + OFF_OP);            // 2x [b*s][f] partials
    float*          linv = (float*)(ws + OFF_LV);           // [h][b][s] 1/rowsum

    const float inv4 = 1.0f / powf((float)D_, 0.25f);

    // 1) casts + weight transposes
    const long n4x = (long)MS * D_ / 4;
    cvt3_k<<<dim3((n4x + 255) / 256, 1, 3), 256, 0, stream>>>(
        Xq, Xk, Xv, Xbq, Xbk, Xbv, n4x);
    transcvt3_k<<<dim3(16, 16, 24), 256, 0, stream>>>(Wq, Wk, Wv, Wqt, Wkt, Wvt);
    transcvt_k<<<dim3(16, 128, 1), 256, 0, stream>>>(Wz, Wzt, HD, D_);

    // 2) q & k projections in ONE dispatch (z1: q/k, z2: head), scaled by inv4
    gemm256_k<<<dim3(2, 16, 16), 512, 0, stream>>>(
        Xbq, Wqt, qb, D_, D_, D_, D_,
        (long)MS * D_, 0, (long)H_ * D_ * D_, (long)D_ * D_,
        (long)H_ * MS * D_, (long)MS * D_, 8, inv4, 0, nullptr, 0, 0);
    // v^T[e][t] = sum_d Wvt[e][d] * Xv[t][d]  (z=(h,b), d2=2)
    gemm256_k<<<dim3(8, 2, 16), 512, 0, stream>>>(
        Wvt, Xbv, vT, D_, D_, D_, SS,
        (long)D_ * D_, 0, 0, (long)SS * D_, (long)2 * D_ * SS, (long)D_ * SS, 2,
        1.0f, 0, nullptr, 0, 0);

    // 3) E = exp(q·k) -> bf16, batched over (h,b). No max-subtraction needed:
    //    logits ~N(0,1), |logit| < ~7, exp safe in fp32/bf16.
    gemm256_k<<<dim3(8, 8, 16), 512, 0, stream>>>(
        qb, qb + (long)H_ * MS * D_, scb, D_, D_, D_, SS,
        (long)MS * D_, (long)SS * D_, (long)MS * D_, (long)SS * D_,
        (long)2 * SS * SS, (long)SS * SS, 2, 1.0f, 1, nullptr, 0, 0);

    // 4) row sums + 1/l + attn_avg (E read once; no probs write-back)
    sumavg_k<<<dim3(BB * SS), 256, 0, stream>>>(scb, attn_avg, linv);

    // 5) PV: z[s][e] = (1/l_s) * sum_t E[s,t]*vT[e,t] -> zal[b*s][h*e]
    //    (normalization folded into epilogue via rowScale=linv)
    gemm256_k<<<dim3(2, 8, 16), 512, 0, stream>>>(
        scb, vT, zal, SS, SS, SS, HD,
        (long)2 * SS * SS, (long)SS * SS, (long)2 * D_ * SS, (long)D_ * SS,
        512, (long)SS * HD, 2, 1.0f, 0,
        linv, (long)BB * SS, (long)SS);

    // 6) out-proj, K-split=2 (z2 halves of he): partials -> combine with bias
    gemm_bt_k<<<dim3(4, 32, 2), 256, 0, stream>>>(
        zal, Wzt, opp, HD / 2, HD, HD, D_,
        0, 2048, 0, 2048, 0, (long)MS * D_, 2, 1.0f, nullptr, 0, 0, nullptr, 0, 0);
    const long n4o = (long)MS * D_ / 4;
    addbias_k<<<dim3((n4o + 255) / 256), 256, 0, stream>>>(
        opp, opp + (long)MS * D_, bz, out);
}